// Round 8
// baseline (940.736 us; speedup 1.0000x reference)
//
#include <hip/hip_runtime.h>

typedef short bf16x8 __attribute__((ext_vector_type(8)));
typedef float f32x4 __attribute__((ext_vector_type(4)));

__device__ __forceinline__ unsigned short f2bf(float f) {
  unsigned u = __float_as_uint(f);
  u += 0x7fffu + ((u >> 16) & 1u);
  return (unsigned short)(u >> 16);
}

__device__ __forceinline__ float bf2f(unsigned short h) {
  return __uint_as_float(((unsigned)h) << 16);
}

__device__ __forceinline__ void gload16(const void* g, void* l) {
  __builtin_amdgcn_global_load_lds((const __attribute__((address_space(1))) void*)g,
                                   (__attribute__((address_space(3))) void*)l, 16, 0, 0);
}

__device__ __forceinline__ bf16x8 rf128(const unsigned char* lds, int row, int pb) {
  return *(const bf16x8*)(lds + row * 128 + (pb ^ ((row & 7) << 4)));
}
__device__ __forceinline__ bf16x8 rf256(const unsigned char* lds, int row, int pb) {
  return *(const bf16x8*)(lds + row * 256 + (pb ^ ((row & 7) << 4)));
}

// ---------------- CSR build ----------------
__global__ void k_hist(const int* __restrict__ dst, int* __restrict__ deg, int E) {
  int e = blockIdx.x * blockDim.x + threadIdx.x;
  if (e < E) atomicAdd(&deg[dst[e]], 1);
}

__global__ __launch_bounds__(256) void k_scan_part(const int* __restrict__ deg,
                                                    int* __restrict__ bsum, int n) {
  int b = blockIdx.x, t = threadIdx.x;
  int base = b * 1024 + t * 4;
  int s = 0;
#pragma unroll
  for (int i = 0; i < 4; i++) {
    int idx = base + i;
    if (idx < n) s += deg[idx];
  }
  for (int off = 1; off < 64; off <<= 1) s += __shfl_xor(s, off);
  __shared__ int ws[4];
  if ((t & 63) == 0) ws[t >> 6] = s;
  __syncthreads();
  if (t == 0) bsum[b] = ws[0] + ws[1] + ws[2] + ws[3];
}

__global__ void k_scan_bsum(const int* __restrict__ bsum, int* __restrict__ boff,
                            int* __restrict__ row_start, int nb, int n) {
  int t = threadIdx.x;
  int orig = (t < nb) ? bsum[t] : 0;
  int v = orig;
  for (int off = 1; off < 64; off <<= 1) {
    int u = __shfl_up(v, off);
    if (t >= off) v += u;
  }
  if (t < nb) boff[t] = v - orig;
  if (t == nb - 1) row_start[n] = v;
}

__global__ __launch_bounds__(256) void k_scan_final(const int* __restrict__ deg,
                                                     const int* __restrict__ boff,
                                                     int* __restrict__ row_start,
                                                     int* __restrict__ cursor, int n) {
  int b = blockIdx.x, t = threadIdx.x;
  int lane = t & 63, wid = t >> 6;
  int base = b * 1024 + t * 4;
  int v[4];
  int s = 0;
#pragma unroll
  for (int i = 0; i < 4; i++) {
    int idx = base + i;
    v[i] = (idx < n) ? deg[idx] : 0;
    s += v[i];
  }
  int sc = s;
  for (int off = 1; off < 64; off <<= 1) {
    int u = __shfl_up(sc, off);
    if (lane >= off) sc += u;
  }
  __shared__ int ws[4];
  if (lane == 63) ws[wid] = sc;
  __syncthreads();
  int wbase = 0;
  for (int i = 0; i < wid; i++) wbase += ws[i];
  int run = boff[b] + wbase + sc - s;
#pragma unroll
  for (int i = 0; i < 4; i++) {
    int idx = base + i;
    if (idx < n) {
      row_start[idx] = run;
      cursor[idx] = run;
      run += v[i];
    }
  }
}

__global__ void k_scatter(const int* __restrict__ src, const int* __restrict__ dst,
                          int* __restrict__ cursor, int* __restrict__ edge_src, int E) {
  int e = blockIdx.x * blockDim.x + threadIdx.x;
  if (e < E) {
    int pos = atomicAdd(&cursor[dst[e]], 1);
    edge_src[pos] = src[e];
  }
}

// ---------------- cast x -> X.h (row stride 640) ----------------
__global__ void k_cast(const float* __restrict__ x, unsigned short* __restrict__ X, int n) {
  int i = blockIdx.x * blockDim.x + threadIdx.x;
  if (i >= n * 32) return;
  int r = i >> 5, c = (i & 31) * 4;
  float4 v = *(const float4*)(x + (size_t)r * 128 + c);
  ushort4 o;
  o.x = f2bf(v.x); o.y = f2bf(v.y); o.z = f2bf(v.z); o.w = f2bf(v.w);
  *(ushort4*)(X + (size_t)r * 640 + c) = o;
}

// ---------------- fold ----------------
__global__ __launch_bounds__(256) void k_fold(const float* __restrict__ post_w,
                                               const float* __restrict__ pre_w,
                                               const float* __restrict__ pre_b,
                                               const float* __restrict__ post_b,
                                               float* __restrict__ Whg,
                                               float* __restrict__ biasg) {
  int id = blockIdx.x * blockDim.x + threadIdx.x;
  if (id >= 3 * 128 * 128) return;
  int g = id >> 14;
  int rem = id & 16383;
  int j = rem >> 7, k = rem & 127;
  const float* pw = post_w + j * 1664 + g * 512 + 128;
  float acc = 0.f, bacc = 0.f;
  for (int f = 0; f < 128; f++) {
    float wc = pw[f] + pw[128 + f] + pw[256 + f];
    acc += wc * pre_w[f * 256 + k];
    if (k == 0) bacc += wc * pre_b[f];
  }
  Whg[id] = acc;
  if (k == 0) biasg[g * 128 + j] = bacc + ((g == 0) ? post_b[j] : 0.f);
}

// ---------------- weight repacks ----------------
__global__ void k_repack_post(const float* __restrict__ post_w, const float* __restrict__ Whg,
                              unsigned char* __restrict__ img) {
  int i = blockIdx.x * blockDim.x + threadIdx.x;
  if (i >= 384 * 640) return;
  int r = i / 640, k = i - r * 640;
  int g = r >> 7, jj = r & 127;
  float v;
  if (k < 128) v = ((g == 0) ? post_w[jj * 1664 + k] : 0.0f) + Whg[(g * 128 + jj) * 128 + k];
  else v = post_w[jj * 1664 + g * 512 + 128 + (k - 128)];
  int kt = k >> 6, kl = k & 63;
  int ch = kl >> 3, e = kl & 7;
  int off = kt * 49152 + r * 128 + ((ch * 16) ^ ((r & 7) << 4)) + e * 2;
  *(unsigned short*)(img + off) = f2bf(v);
}

__global__ void k_repack_q(const float* __restrict__ pre_w, unsigned char* __restrict__ img) {
  int i = blockIdx.x * blockDim.x + threadIdx.x;
  if (i >= 128 * 128) return;
  int j = i >> 7, k = i & 127;
  int ch = k >> 3, e = k & 7;
  int off = j * 256 + ((ch * 16) ^ ((j & 7) << 4)) + e * 2;
  *(unsigned short*)(img + off) = f2bf(pre_w[j * 256 + 128 + k]);
}

__global__ void k_repack_lin(const float* __restrict__ lin_w, unsigned char* __restrict__ img) {
  int i = blockIdx.x * blockDim.x + threadIdx.x;
  if (i >= 128 * 128) return;
  int j = i >> 7, k = i & 127;
  int ch = k >> 3, e = k & 7;
  int off = j * 256 + ((ch * 16) ^ ((j & 7) << 4)) + e * 2;
  *(unsigned short*)(img + off) = f2bf(lin_w[i]);
}

// ---------------- GEMM1 (layer 0 only): Qb0 = X.h @ Wq^T ----------------
__global__ __launch_bounds__(512, 2) void k_gemm1(const unsigned short* __restrict__ X,
                                                   const unsigned char* __restrict__ Qimg,
                                                   unsigned short* __restrict__ Qb) {
  __shared__ __align__(16) unsigned char lds[65536];
  int tid = threadIdx.x;
  int w = tid >> 6, lane = tid & 63;
  int wr = w >> 2, wc = w & 3;
  int l16 = lane & 15, lhi = lane >> 4;
  int row0 = blockIdx.x * 128;
  const char* Xb = (const char*)X;
#pragma unroll
  for (int j = 0; j < 4; j++) {
    int off = w * 4096 + j * 1024 + lane * 16;
    int r = off >> 8, pos = off & 255;
    int ch = (pos ^ ((r & 7) << 4)) >> 4;
    gload16(Xb + (size_t)(row0 + r) * 1280 + ch * 16, lds + w * 4096 + j * 1024);
  }
#pragma unroll
  for (int j = 0; j < 4; j++) {
    int off = w * 4096 + j * 1024;
    gload16(Qimg + off + lane * 16, lds + 32768 + off);
  }
  __syncthreads();
  f32x4 acc[4][2];
#pragma unroll
  for (int m = 0; m < 4; m++)
#pragma unroll
    for (int j = 0; j < 2; j++) acc[m][j] = (f32x4){0.f, 0.f, 0.f, 0.f};
#pragma unroll
  for (int ks = 0; ks < 4; ks++) {
    int pb = ks * 64 + lhi * 16;
    bf16x8 af[4], bfr[2];
#pragma unroll
    for (int m = 0; m < 4; m++) af[m] = rf256(lds, wr * 64 + m * 16 + l16, pb);
#pragma unroll
    for (int j = 0; j < 2; j++) bfr[j] = rf256(lds + 32768, wc * 32 + j * 16 + l16, pb);
#pragma unroll
    for (int m = 0; m < 4; m++)
#pragma unroll
      for (int j = 0; j < 2; j++)
        acc[m][j] = __builtin_amdgcn_mfma_f32_16x16x32_bf16(af[m], bfr[j], acc[m][j], 0, 0, 0);
  }
#pragma unroll
  for (int m = 0; m < 4; m++)
#pragma unroll
    for (int j = 0; j < 2; j++)
#pragma unroll
      for (int i = 0; i < 4; i++) {
        int r = row0 + wr * 64 + m * 16 + lhi * 4 + i;
        int c = wc * 32 + j * 16 + l16;
        Qb[(size_t)r * 128 + c] = f2bf(acc[m][j][i]);
      }
}

// ------- fused: AGG (phase 0) + post GEMM + combine + lin GEMM + relu + next-Q GEMM -------
__global__ __launch_bounds__(512, 2) void k_fused(unsigned short* __restrict__ X,
                                                   const unsigned short* __restrict__ QbIn,
                                                   const unsigned char* __restrict__ Bimg,
                                                   const unsigned char* __restrict__ Limg,
                                                   const unsigned char* __restrict__ Qimg,
                                                   const int* __restrict__ row_start,
                                                   const int* __restrict__ edge_src,
                                                   const float* __restrict__ pre_w,
                                                   const float* __restrict__ pre_b,
                                                   const float* __restrict__ adl,
                                                   const float* __restrict__ biasg,
                                                   const float* __restrict__ lin_b,
                                                   unsigned short* __restrict__ QbOut,
                                                   float* __restrict__ Fout,
                                                   int n, int write_f32, int doC) {
  // dbuf phase A: buf b: A[16KB] @ b*65536, B[48KB] @ b*65536+16384
  // phase B: lin @0, y @32768; phase C: h @65536, Wq @98304; scale/invs @131072
  __shared__ __align__(16) unsigned char lds[132096];
  float* lds_scale = (float*)(lds + 131072);
  float* lds_invs = (float*)(lds + 131072 + 512);
  int tid = threadIdx.x;
  int w = tid >> 6, lane = tid & 63;
  int wr = w >> 2, wc = w & 3;
  int l16 = lane & 15, lhi = lane >> 4;
  int row0 = blockIdx.x * 128;

  // ---- phase 0: aggregate this block's 128 nodes (wave w -> nodes w*16..w*16+15) ----
  for (int t = 0; t < 16; t++) {
    int v = row0 + w * 16 + t;
    float m0, m1, n0, n1, x0v, x1v, sd0, sd1, sc;
    bool valid = (v < n);
    int dg = 0;
    if (valid) {
      int r0 = row_start[v], r1 = row_start[v + 1];
      dg = r1 - r0;
      if (dg > 0) {
        float s0 = 0.f, s1 = 0.f, q0 = 0.f, q1 = 0.f;
        float mn0 = INFINITY, mn1 = INFINITY, mx0 = -INFINITY, mx1 = -INFINITY;
        int e = r0;
        for (; e + 7 < r1; e += 8) {
          float vx[8], vy[8];
#pragma unroll
          for (int u = 0; u < 8; u++) {
            int s = edge_src[e + u];
            unsigned uu = *(const unsigned*)(QbIn + (size_t)s * 128 + 2 * lane);
            vx[u] = __uint_as_float(uu << 16);
            vy[u] = __uint_as_float(uu & 0xffff0000u);
          }
#pragma unroll
          for (int u = 0; u < 8; u++) {
            s0 += vx[u]; s1 += vy[u];
            q0 += vx[u] * vx[u]; q1 += vy[u] * vy[u];
            mn0 = fminf(mn0, vx[u]); mn1 = fminf(mn1, vy[u]);
            mx0 = fmaxf(mx0, vx[u]); mx1 = fmaxf(mx1, vy[u]);
          }
        }
        for (; e < r1; e++) {
          int s = edge_src[e];
          unsigned uu = *(const unsigned*)(QbIn + (size_t)s * 128 + 2 * lane);
          float ax = __uint_as_float(uu << 16), ay = __uint_as_float(uu & 0xffff0000u);
          s0 += ax; s1 += ay;
          q0 += ax * ax; q1 += ay * ay;
          mn0 = fminf(mn0, ax); mn1 = fminf(mn1, ay);
          mx0 = fmaxf(mx0, ax); mx1 = fmaxf(mx1, ay);
        }
        float invd = 1.0f / (float)dg;
        m0 = s0 * invd; m1 = s1 * invd;
        float var0 = fmaxf(q0 * invd - m0 * m0, 0.f);
        float var1 = fmaxf(q1 * invd - m1 * m1, 0.f);
        sd0 = sqrtf(var0 + 1e-5f); sd1 = sqrtf(var1 + 1e-5f);
        n0 = mn0; n1 = mn1; x0v = mx0; x1v = mx1;
      } else {
        // rare: cancel folded c-term by storing -c
        int j0 = 2 * lane, j1 = 2 * lane + 1;
        float c0 = pre_b[j0], c1 = pre_b[j1];
        const unsigned short* hv = X + (size_t)v * 640;
        for (int k = 0; k < 128; k++) {
          float hk = bf2f(hv[k]);
          c0 += hk * pre_w[j0 * 256 + k];
          c1 += hk * pre_w[j1 * 256 + k];
        }
        m0 = n0 = x0v = -c0;
        m1 = n1 = x1v = -c1;
        sd0 = sd1 = sqrtf(1e-5f);
      }
      sc = logf(fmaxf((float)dg, 1.0f) + 1.0f) / adl[0];
    } else {
      m0 = m1 = n0 = n1 = x0v = x1v = 0.f;
      sd0 = sd1 = 0.f;
      sc = 1.0f;
    }
    unsigned short* row = X + (size_t)v * 640 + 128;
    ushort2 w0; w0.x = f2bf(m0);  w0.y = f2bf(m1);
    ushort2 w1; w1.x = f2bf(n0);  w1.y = f2bf(n1);
    ushort2 w2; w2.x = f2bf(x0v); w2.y = f2bf(x1v);
    ushort2 w3; w3.x = f2bf(sd0); w3.y = f2bf(sd1);
    *(ushort2*)(row + 2 * lane) = w0;
    *(ushort2*)(row + 128 + 2 * lane) = w1;
    *(ushort2*)(row + 256 + 2 * lane) = w2;
    *(ushort2*)(row + 384 + 2 * lane) = w3;
    if (lane == 0) {
      lds_scale[v - row0] = sc;
      lds_invs[v - row0] = 1.0f / sc;
    }
  }
  __syncthreads();  // agg stores drained (vmcnt 0) -> visible to gload16 below

  // ---- phase A: y_pre = X @ Bpost^T (K=640), double-buffered ----
  const char* Xb = (const char*)X;
  const char* srcA[2];
  unsigned dstA[2];
#pragma unroll
  for (int j = 0; j < 2; j++) {
    int off = (w * 2 + j) * 1024 + lane * 16;
    int r = off >> 7, pos = off & 127;
    int ch = (pos ^ ((r & 7) << 4)) >> 4;
    srcA[j] = Xb + (size_t)(row0 + r) * 1280 + ch * 16;
    dstA[j] = (w * 2 + j) * 1024;
  }
  const unsigned char* srcB = Bimg + w * 6144 + lane * 16;
  unsigned dstB = 16384 + w * 6144;

  f32x4 acc[4][6];
#pragma unroll
  for (int m = 0; m < 4; m++)
#pragma unroll
    for (int f = 0; f < 6; f++) acc[m][f] = (f32x4){0.f, 0.f, 0.f, 0.f};

#define STAGE_AB(buf, kt)                                                        \
  do {                                                                           \
    unsigned base = (buf) * 65536u;                                              \
    _Pragma("unroll") for (int j = 0; j < 2; j++)                                \
        gload16(srcA[j] + (kt) * 128, lds + base + dstA[j]);                     \
    _Pragma("unroll") for (int j = 0; j < 6; j++)                                \
        gload16(srcB + (size_t)(kt) * 49152 + j * 1024, lds + base + dstB + j * 1024); \
  } while (0)

#define COMPUTE_A(buf)                                                           \
  do {                                                                           \
    const unsigned char* LA = lds + (buf) * 65536u;                              \
    const unsigned char* LB = LA + 16384;                                        \
    _Pragma("unroll") for (int ks = 0; ks < 2; ks++) {                           \
      int pb = ks * 64 + lhi * 16;                                               \
      bf16x8 af[4], bfr[6];                                                      \
      _Pragma("unroll") for (int m = 0; m < 4; m++)                              \
          af[m] = rf128(LA, wr * 64 + m * 16 + l16, pb);                         \
      _Pragma("unroll") for (int f = 0; f < 6; f++)                              \
          bfr[f] = rf128(LB, (f >> 1) * 128 + wc * 32 + (f & 1) * 16 + l16, pb); \
      _Pragma("unroll") for (int m = 0; m < 4; m++)                              \
          _Pragma("unroll") for (int f = 0; f < 6; f++)                          \
              acc[m][f] =                                                        \
                  __builtin_amdgcn_mfma_f32_16x16x32_bf16(af[m], bfr[f], acc[m][f], 0, 0, 0); \
    }                                                                            \
  } while (0)

  STAGE_AB(0, 0);
  __syncthreads();
  for (int kt = 0; kt < 9; kt++) {
    STAGE_AB((kt + 1) & 1, kt + 1);
    COMPUTE_A(kt & 1);
    __syncthreads();
  }
  // prefetch lin image into @0 while computing final tile (buf1)
#pragma unroll
  for (int j = 0; j < 4; j++) {
    int off = w * 4096 + j * 1024;
    gload16(Limg + off + lane * 16, lds + off);
  }
  COMPUTE_A(1);

  // combine epilogue -> y into LDS @32768 (256B swizzled rows)
#pragma unroll
  for (int m = 0; m < 4; m++)
#pragma unroll
    for (int i = 0; i < 4; i++) {
      int rl = wr * 64 + m * 16 + lhi * 4 + i;
      float s = lds_scale[rl], iv = lds_invs[rl];
      int swz = (rl & 7) << 4;
#pragma unroll
      for (int j = 0; j < 2; j++) {
        int c = wc * 32 + j * 16 + l16;
        float v = acc[m][j][i] + s * acc[m][2 + j][i] + iv * acc[m][4 + j][i] + biasg[c] +
                  s * biasg[128 + c] + iv * biasg[256 + c];
        *(unsigned short*)(lds + 32768 + rl * 256 + ((2 * c) ^ swz)) = f2bf(v);
      }
    }
  __syncthreads();  // drains lin stage + makes y visible

  // issue next-layer Wq prefetch into @98304 (hides under phase B)
  if (doC) {
#pragma unroll
    for (int j = 0; j < 4; j++) {
      int off = w * 4096 + j * 1024;
      gload16(Qimg + off + lane * 16, lds + 98304 + off);
    }
  }

  // phase B: h = relu(y @ lin^T + lin_b)
  f32x4 acc2[4][2];
#pragma unroll
  for (int m = 0; m < 4; m++)
#pragma unroll
    for (int j = 0; j < 2; j++) acc2[m][j] = (f32x4){0.f, 0.f, 0.f, 0.f};
#pragma unroll
  for (int ks = 0; ks < 4; ks++) {
    int pb = ks * 64 + lhi * 16;
    bf16x8 af[4], bfr[2];
#pragma unroll
    for (int m = 0; m < 4; m++) af[m] = rf256(lds + 32768, wr * 64 + m * 16 + l16, pb);
#pragma unroll
    for (int j = 0; j < 2; j++) bfr[j] = rf256(lds, wc * 32 + j * 16 + l16, pb);
#pragma unroll
    for (int m = 0; m < 4; m++)
#pragma unroll
      for (int j = 0; j < 2; j++)
        acc2[m][j] = __builtin_amdgcn_mfma_f32_16x16x32_bf16(af[m], bfr[j], acc2[m][j], 0, 0, 0);
  }
  // h epilogue: write X.h global (+Fout), and h into LDS @65536 for phase C
#pragma unroll
  for (int m = 0; m < 4; m++)
#pragma unroll
    for (int j = 0; j < 2; j++)
#pragma unroll
      for (int i = 0; i < 4; i++) {
        int rl = wr * 64 + m * 16 + lhi * 4 + i;
        int r = row0 + rl;
        int c = wc * 32 + j * 16 + l16;
        float v = fmaxf(acc2[m][j][i] + lin_b[c], 0.0f);
        unsigned short hb = f2bf(v);
        X[(size_t)r * 640 + c] = hb;
        if (doC) *(unsigned short*)(lds + 65536 + rl * 256 + ((2 * c) ^ ((rl & 7) << 4))) = hb;
        if (write_f32 && r < n) Fout[(size_t)r * 128 + c] = v;
      }
  if (!doC) return;
  __syncthreads();  // h visible + Wq staged (vmcnt drained)

  // phase C: Qb_next = h @ Wq^T
  f32x4 acc3[4][2];
#pragma unroll
  for (int m = 0; m < 4; m++)
#pragma unroll
    for (int j = 0; j < 2; j++) acc3[m][j] = (f32x4){0.f, 0.f, 0.f, 0.f};
#pragma unroll
  for (int ks = 0; ks < 4; ks++) {
    int pb = ks * 64 + lhi * 16;
    bf16x8 af[4], bfr[2];
#pragma unroll
    for (int m = 0; m < 4; m++) af[m] = rf256(lds + 65536, wr * 64 + m * 16 + l16, pb);
#pragma unroll
    for (int j = 0; j < 2; j++) bfr[j] = rf256(lds + 98304, wc * 32 + j * 16 + l16, pb);
#pragma unroll
    for (int m = 0; m < 4; m++)
#pragma unroll
      for (int j = 0; j < 2; j++)
        acc3[m][j] = __builtin_amdgcn_mfma_f32_16x16x32_bf16(af[m], bfr[j], acc3[m][j], 0, 0, 0);
  }
#pragma unroll
  for (int m = 0; m < 4; m++)
#pragma unroll
    for (int j = 0; j < 2; j++)
#pragma unroll
      for (int i = 0; i < 4; i++) {
        int r = row0 + wr * 64 + m * 16 + lhi * 4 + i;
        int c = wc * 32 + j * 16 + l16;
        QbOut[(size_t)r * 128 + c] = f2bf(acc3[m][j][i]);
      }
#undef STAGE_AB
#undef COMPUTE_A
}

// ---------------- host ----------------
extern "C" void kernel_launch(void* const* d_in, const int* in_sizes, int n_in,
                              void* d_out, int out_size, void* d_ws, size_t ws_size,
                              hipStream_t stream) {
  const float* x = (const float*)d_in[0];
  const int* eidx = (const int*)d_in[1];
  int n = in_sizes[0] / 128;
  int E = in_sizes[1] / 2;
  int n_pad = (n + 127) & ~127;
  const int* src = eidx;
  const int* dst = eidx + E;

  const float *pre_w[5], *pre_b[5], *adl[5], *post_w[5], *post_b[5], *lin_w[5], *lin_b[5];
  for (int i = 0; i < 5; i++) {
    pre_w[i] = (const float*)d_in[2 + i * 7 + 0];
    pre_b[i] = (const float*)d_in[2 + i * 7 + 1];
    adl[i] = (const float*)d_in[2 + i * 7 + 2];
    post_w[i] = (const float*)d_in[2 + i * 7 + 3];
    post_b[i] = (const float*)d_in[2 + i * 7 + 4];
    lin_w[i] = (const float*)d_in[2 + i * 7 + 5];
    lin_b[i] = (const float*)d_in[2 + i * 7 + 6];
  }

  char* ws = (char*)d_ws;
  size_t off = 0;
  auto alloc = [&](size_t bytes) {
    char* p = ws + off;
    off += (bytes + 255) & ~(size_t)255;
    return p;
  };
  unsigned short* X = (unsigned short*)alloc((size_t)n_pad * 640 * 2);  // [h | agg]
  unsigned short* Qb0 = (unsigned short*)alloc((size_t)n_pad * 128 * 2);
  unsigned short* Qb1 = (unsigned short*)alloc((size_t)n_pad * 128 * 2);
  int* deg = (int*)alloc((size_t)n * 4);
  int* row_start = (int*)alloc((size_t)(n + 1) * 4);
  int* cursor = (int*)alloc((size_t)n * 4);
  int* edge_src = (int*)alloc((size_t)E * 4);
  int nb = (n + 1023) / 1024;
  int* bsum = (int*)alloc((size_t)nb * 4);
  int* boff = (int*)alloc((size_t)nb * 4);
  float* Whg = (float*)alloc(3 * 128 * 128 * 4);
  unsigned char *Bpost[5], *Lin[5], *Qimg[5];
  float* biasg[5];
  for (int i = 0; i < 5; i++) {
    Bpost[i] = (unsigned char*)alloc(491520);
    Lin[i] = (unsigned char*)alloc(32768);
    Qimg[i] = (unsigned char*)alloc(32768);
    biasg[i] = (float*)alloc(384 * 4);
  }

  hipMemsetAsync(deg, 0, (size_t)n * 4, stream);
  k_hist<<<(E + 255) / 256, 256, 0, stream>>>(dst, deg, E);
  k_scan_part<<<nb, 256, 0, stream>>>(deg, bsum, n);
  k_scan_bsum<<<1, 64, 0, stream>>>(bsum, boff, row_start, nb, n);
  k_scan_final<<<nb, 256, 0, stream>>>(deg, boff, row_start, cursor, n);
  k_scatter<<<(E + 255) / 256, 256, 0, stream>>>(src, dst, cursor, edge_src, E);
  k_cast<<<(n * 32 + 255) / 256, 256, 0, stream>>>(x, X, n);
  for (int i = 0; i < 5; i++) {
    k_fold<<<192, 256, 0, stream>>>(post_w[i], pre_w[i], pre_b[i], post_b[i], Whg, biasg[i]);
    k_repack_post<<<(384 * 640 + 255) / 256, 256, 0, stream>>>(post_w[i], Whg, Bpost[i]);
    k_repack_lin<<<(128 * 128 + 255) / 256, 256, 0, stream>>>(lin_w[i], Lin[i]);
    k_repack_q<<<(128 * 128 + 255) / 256, 256, 0, stream>>>(pre_w[i], Qimg[i]);
  }

  int gblocks = n_pad / 128;
  k_gemm1<<<gblocks, 512, 0, stream>>>(X, Qimg[0], Qb0);
  for (int L = 0; L < 5; L++) {
    unsigned short* QbIn = (L & 1) ? Qb1 : Qb0;
    unsigned short* QbOut = (L & 1) ? Qb0 : Qb1;
    k_fused<<<gblocks, 512, 0, stream>>>(X, QbIn, Bpost[L], Lin[L],
                                         (L < 4) ? Qimg[L + 1] : Qimg[0], row_start, edge_src,
                                         pre_w[L], pre_b[L], adl[L], biasg[L], lin_b[L], QbOut,
                                         (float*)d_out, n, (L == 4) ? 1 : 0, (L < 4) ? 1 : 0);
  }
}

// Round 9
// 635.377 us; speedup vs baseline: 1.4806x; 1.4806x over previous
//
#include <hip/hip_runtime.h>

typedef short bf16x8 __attribute__((ext_vector_type(8)));
typedef float f32x4 __attribute__((ext_vector_type(4)));

__device__ __forceinline__ unsigned short f2bf(float f) {
  unsigned u = __float_as_uint(f);
  u += 0x7fffu + ((u >> 16) & 1u);
  return (unsigned short)(u >> 16);
}

__device__ __forceinline__ float bf2f(unsigned short h) {
  return __uint_as_float(((unsigned)h) << 16);
}

__device__ __forceinline__ void gload16(const void* g, void* l) {
  __builtin_amdgcn_global_load_lds((const __attribute__((address_space(1))) void*)g,
                                   (__attribute__((address_space(3))) void*)l, 16, 0, 0);
}

__device__ __forceinline__ bf16x8 rf128(const unsigned char* lds, int row, int pb) {
  return *(const bf16x8*)(lds + row * 128 + (pb ^ ((row & 7) << 4)));
}
__device__ __forceinline__ bf16x8 rf256(const unsigned char* lds, int row, int pb) {
  return *(const bf16x8*)(lds + row * 256 + (pb ^ ((row & 7) << 4)));
}

// ---------------- CSR build ----------------
__global__ void k_hist(const int* __restrict__ dst, int* __restrict__ deg, int E) {
  int e = blockIdx.x * blockDim.x + threadIdx.x;
  if (e < E) atomicAdd(&deg[dst[e]], 1);
}

__global__ __launch_bounds__(256) void k_scan_part(const int* __restrict__ deg,
                                                    int* __restrict__ bsum, int n) {
  int b = blockIdx.x, t = threadIdx.x;
  int base = b * 1024 + t * 4;
  int s = 0;
#pragma unroll
  for (int i = 0; i < 4; i++) {
    int idx = base + i;
    if (idx < n) s += deg[idx];
  }
  for (int off = 1; off < 64; off <<= 1) s += __shfl_xor(s, off);
  __shared__ int ws[4];
  if ((t & 63) == 0) ws[t >> 6] = s;
  __syncthreads();
  if (t == 0) bsum[b] = ws[0] + ws[1] + ws[2] + ws[3];
}

__global__ void k_scan_bsum(const int* __restrict__ bsum, int* __restrict__ boff,
                            int* __restrict__ row_start, int nb, int n) {
  int t = threadIdx.x;
  int orig = (t < nb) ? bsum[t] : 0;
  int v = orig;
  for (int off = 1; off < 64; off <<= 1) {
    int u = __shfl_up(v, off);
    if (t >= off) v += u;
  }
  if (t < nb) boff[t] = v - orig;
  if (t == nb - 1) row_start[n] = v;
}

__global__ __launch_bounds__(256) void k_scan_final(const int* __restrict__ deg,
                                                     const int* __restrict__ boff,
                                                     int* __restrict__ row_start,
                                                     int* __restrict__ cursor, int n) {
  int b = blockIdx.x, t = threadIdx.x;
  int lane = t & 63, wid = t >> 6;
  int base = b * 1024 + t * 4;
  int v[4];
  int s = 0;
#pragma unroll
  for (int i = 0; i < 4; i++) {
    int idx = base + i;
    v[i] = (idx < n) ? deg[idx] : 0;
    s += v[i];
  }
  int sc = s;
  for (int off = 1; off < 64; off <<= 1) {
    int u = __shfl_up(sc, off);
    if (lane >= off) sc += u;
  }
  __shared__ int ws[4];
  if (lane == 63) ws[wid] = sc;
  __syncthreads();
  int wbase = 0;
  for (int i = 0; i < wid; i++) wbase += ws[i];
  int run = boff[b] + wbase + sc - s;
#pragma unroll
  for (int i = 0; i < 4; i++) {
    int idx = base + i;
    if (idx < n) {
      row_start[idx] = run;
      cursor[idx] = run;
      run += v[i];
    }
  }
}

__global__ void k_scatter(const int* __restrict__ src, const int* __restrict__ dst,
                          int* __restrict__ cursor, int* __restrict__ edge_src, int E) {
  int e = blockIdx.x * blockDim.x + threadIdx.x;
  if (e < E) {
    int pos = atomicAdd(&cursor[dst[e]], 1);
    edge_src[pos] = src[e];
  }
}

// ---------------- cast x -> X.h (row stride 640) ----------------
__global__ void k_cast(const float* __restrict__ x, unsigned short* __restrict__ X, int n) {
  int i = blockIdx.x * blockDim.x + threadIdx.x;
  if (i >= n * 32) return;
  int r = i >> 5, c = (i & 31) * 4;
  float4 v = *(const float4*)(x + (size_t)r * 128 + c);
  ushort4 o;
  o.x = f2bf(v.x); o.y = f2bf(v.y); o.z = f2bf(v.z); o.w = f2bf(v.w);
  *(ushort4*)(X + (size_t)r * 640 + c) = o;
}

// ---------------- fold ----------------
__global__ __launch_bounds__(256) void k_fold(const float* __restrict__ post_w,
                                               const float* __restrict__ pre_w,
                                               const float* __restrict__ pre_b,
                                               const float* __restrict__ post_b,
                                               float* __restrict__ Whg,
                                               float* __restrict__ biasg) {
  int id = blockIdx.x * blockDim.x + threadIdx.x;
  if (id >= 3 * 128 * 128) return;
  int g = id >> 14;
  int rem = id & 16383;
  int j = rem >> 7, k = rem & 127;
  const float* pw = post_w + j * 1664 + g * 512 + 128;
  float acc = 0.f, bacc = 0.f;
  for (int f = 0; f < 128; f++) {
    float wc = pw[f] + pw[128 + f] + pw[256 + f];
    acc += wc * pre_w[f * 256 + k];
    if (k == 0) bacc += wc * pre_b[f];
  }
  Whg[id] = acc;
  if (k == 0) biasg[g * 128 + j] = bacc + ((g == 0) ? post_b[j] : 0.f);
}

// ---------------- weight repacks ----------------
__global__ void k_repack_post(const float* __restrict__ post_w, const float* __restrict__ Whg,
                              unsigned char* __restrict__ img) {
  int i = blockIdx.x * blockDim.x + threadIdx.x;
  if (i >= 384 * 640) return;
  int r = i / 640, k = i - r * 640;
  int g = r >> 7, jj = r & 127;
  float v;
  if (k < 128) v = ((g == 0) ? post_w[jj * 1664 + k] : 0.0f) + Whg[(g * 128 + jj) * 128 + k];
  else v = post_w[jj * 1664 + g * 512 + 128 + (k - 128)];
  int kt = k >> 6, kl = k & 63;
  int ch = kl >> 3, e = kl & 7;
  int off = kt * 49152 + r * 128 + ((ch * 16) ^ ((r & 7) << 4)) + e * 2;
  *(unsigned short*)(img + off) = f2bf(v);
}

__global__ void k_repack_q(const float* __restrict__ pre_w, unsigned char* __restrict__ img) {
  int i = blockIdx.x * blockDim.x + threadIdx.x;
  if (i >= 128 * 128) return;
  int j = i >> 7, k = i & 127;
  int ch = k >> 3, e = k & 7;
  int off = j * 256 + ((ch * 16) ^ ((j & 7) << 4)) + e * 2;
  *(unsigned short*)(img + off) = f2bf(pre_w[j * 256 + 128 + k]);
}

__global__ void k_repack_lin(const float* __restrict__ lin_w, unsigned char* __restrict__ img) {
  int i = blockIdx.x * blockDim.x + threadIdx.x;
  if (i >= 128 * 128) return;
  int j = i >> 7, k = i & 127;
  int ch = k >> 3, e = k & 7;
  int off = j * 256 + ((ch * 16) ^ ((j & 7) << 4)) + e * 2;
  *(unsigned short*)(img + off) = f2bf(lin_w[i]);
}

// ---------------- GEMM1 (layer 0 only): Qb = X.h @ Wq^T ----------------
__global__ __launch_bounds__(512, 2) void k_gemm1(const unsigned short* __restrict__ X,
                                                   const unsigned char* __restrict__ Qimg,
                                                   unsigned short* __restrict__ Qb) {
  __shared__ __align__(16) unsigned char lds[65536];
  int tid = threadIdx.x;
  int w = tid >> 6, lane = tid & 63;
  int wr = w >> 2, wc = w & 3;
  int l16 = lane & 15, lhi = lane >> 4;
  int row0 = blockIdx.x * 128;
  const char* Xb = (const char*)X;
#pragma unroll
  for (int j = 0; j < 4; j++) {
    int off = w * 4096 + j * 1024 + lane * 16;
    int r = off >> 8, pos = off & 255;
    int ch = (pos ^ ((r & 7) << 4)) >> 4;
    gload16(Xb + (size_t)(row0 + r) * 1280 + ch * 16, lds + w * 4096 + j * 1024);
  }
#pragma unroll
  for (int j = 0; j < 4; j++) {
    int off = w * 4096 + j * 1024;
    gload16(Qimg + off + lane * 16, lds + 32768 + off);
  }
  __syncthreads();
  f32x4 acc[4][2];
#pragma unroll
  for (int m = 0; m < 4; m++)
#pragma unroll
    for (int j = 0; j < 2; j++) acc[m][j] = (f32x4){0.f, 0.f, 0.f, 0.f};
#pragma unroll
  for (int ks = 0; ks < 4; ks++) {
    int pb = ks * 64 + lhi * 16;
    bf16x8 af[4], bfr[2];
#pragma unroll
    for (int m = 0; m < 4; m++) af[m] = rf256(lds, wr * 64 + m * 16 + l16, pb);
#pragma unroll
    for (int j = 0; j < 2; j++) bfr[j] = rf256(lds + 32768, wc * 32 + j * 16 + l16, pb);
#pragma unroll
    for (int m = 0; m < 4; m++)
#pragma unroll
      for (int j = 0; j < 2; j++)
        acc[m][j] = __builtin_amdgcn_mfma_f32_16x16x32_bf16(af[m], bfr[j], acc[m][j], 0, 0, 0);
  }
#pragma unroll
  for (int m = 0; m < 4; m++)
#pragma unroll
    for (int j = 0; j < 2; j++)
#pragma unroll
      for (int i = 0; i < 4; i++) {
        int r = row0 + wr * 64 + m * 16 + lhi * 4 + i;
        int c = wc * 32 + j * 16 + l16;
        Qb[(size_t)r * 128 + c] = f2bf(acc[m][j][i]);
      }
}

// ---------------- aggregation: half-wave edge pairing, uint2 loads ----------------
__global__ __launch_bounds__(256) void k_agg(const unsigned short* __restrict__ Qb,
                                              const int* __restrict__ row_start,
                                              const int* __restrict__ edge_src,
                                              const unsigned short* __restrict__ X_h,
                                              const float* __restrict__ pre_w,
                                              const float* __restrict__ pre_b,
                                              const float* __restrict__ adl,
                                              unsigned short* __restrict__ X,
                                              float* __restrict__ scale,
                                              float* __restrict__ inv_scale, int n) {
  int gtid = blockIdx.x * blockDim.x + threadIdx.x;
  int v = gtid >> 6;
  if (v >= n) return;
  int lane = threadIdx.x & 63;
  int half = lane >> 5, fl = lane & 31;  // lane handles features 4*fl..4*fl+3; half = edge parity
  int r0 = row_start[v], r1 = row_start[v + 1];
  int dg = r1 - r0;
  float mean[4], mnv[4], mxv[4], sdv[4];
  if (dg > 0) {
    float s[4] = {0.f, 0.f, 0.f, 0.f}, q[4] = {0.f, 0.f, 0.f, 0.f};
    float mn[4], mx[4];
#pragma unroll
    for (int t = 0; t < 4; t++) { mn[t] = INFINITY; mx[t] = -INFINITY; }
    const unsigned char* qbase = (const unsigned char*)Qb;
    int e = r0 + half;
    for (; e + 6 < r1; e += 8) {  // 4 rows in flight per half
      uint2 u[4];
#pragma unroll
      for (int t = 0; t < 4; t++) {
        int s_ = edge_src[e + 2 * t];
        u[t] = *(const uint2*)(qbase + (size_t)s_ * 256 + 8 * fl);
      }
#pragma unroll
      for (int t = 0; t < 4; t++) {
        float f0 = __uint_as_float(u[t].x << 16);
        float f1 = __uint_as_float(u[t].x & 0xffff0000u);
        float f2 = __uint_as_float(u[t].y << 16);
        float f3 = __uint_as_float(u[t].y & 0xffff0000u);
        s[0] += f0; s[1] += f1; s[2] += f2; s[3] += f3;
        q[0] += f0 * f0; q[1] += f1 * f1; q[2] += f2 * f2; q[3] += f3 * f3;
        mn[0] = fminf(mn[0], f0); mn[1] = fminf(mn[1], f1);
        mn[2] = fminf(mn[2], f2); mn[3] = fminf(mn[3], f3);
        mx[0] = fmaxf(mx[0], f0); mx[1] = fmaxf(mx[1], f1);
        mx[2] = fmaxf(mx[2], f2); mx[3] = fmaxf(mx[3], f3);
      }
    }
    for (; e < r1; e += 2) {
      int s_ = edge_src[e];
      uint2 u = *(const uint2*)(qbase + (size_t)s_ * 256 + 8 * fl);
      float f0 = __uint_as_float(u.x << 16);
      float f1 = __uint_as_float(u.x & 0xffff0000u);
      float f2 = __uint_as_float(u.y << 16);
      float f3 = __uint_as_float(u.y & 0xffff0000u);
      s[0] += f0; s[1] += f1; s[2] += f2; s[3] += f3;
      q[0] += f0 * f0; q[1] += f1 * f1; q[2] += f2 * f2; q[3] += f3 * f3;
      mn[0] = fminf(mn[0], f0); mn[1] = fminf(mn[1], f1);
      mn[2] = fminf(mn[2], f2); mn[3] = fminf(mn[3], f3);
      mx[0] = fmaxf(mx[0], f0); mx[1] = fmaxf(mx[1], f1);
      mx[2] = fmaxf(mx[2], f2); mx[3] = fmaxf(mx[3], f3);
    }
    // combine the two halves (lane L <-> lane L+32 hold same features)
#pragma unroll
    for (int t = 0; t < 4; t++) {
      s[t] += __shfl_xor(s[t], 32);
      q[t] += __shfl_xor(q[t], 32);
      mn[t] = fminf(mn[t], __shfl_xor(mn[t], 32));
      mx[t] = fmaxf(mx[t], __shfl_xor(mx[t], 32));
    }
    float invd = 1.0f / (float)dg;
#pragma unroll
    for (int t = 0; t < 4; t++) {
      mean[t] = s[t] * invd;
      float var = fmaxf(q[t] * invd - mean[t] * mean[t], 0.f);
      sdv[t] = sqrtf(var + 1e-5f);
      mnv[t] = mn[t]; mxv[t] = mx[t];
    }
  } else {
    // rare: cancel folded c-term by storing -c
    if (half == 0) {
      const unsigned short* hv = X_h + (size_t)v * 640;
#pragma unroll
      for (int t = 0; t < 4; t++) {
        int j = 4 * fl + t;
        float c = pre_b[j];
        for (int k = 0; k < 128; k++) c += bf2f(hv[k]) * pre_w[j * 256 + k];
        mean[t] = mnv[t] = mxv[t] = -c;
        sdv[t] = sqrtf(1e-5f);
      }
    }
  }
  if (half == 0) {
    unsigned short* row = X + (size_t)v * 640 + 128;
    ushort4 wm, wn, wx, ws;
    wm.x = f2bf(mean[0]); wm.y = f2bf(mean[1]); wm.z = f2bf(mean[2]); wm.w = f2bf(mean[3]);
    wn.x = f2bf(mnv[0]);  wn.y = f2bf(mnv[1]);  wn.z = f2bf(mnv[2]);  wn.w = f2bf(mnv[3]);
    wx.x = f2bf(mxv[0]);  wx.y = f2bf(mxv[1]);  wx.z = f2bf(mxv[2]);  wx.w = f2bf(mxv[3]);
    ws.x = f2bf(sdv[0]);  ws.y = f2bf(sdv[1]);  ws.z = f2bf(sdv[2]);  ws.w = f2bf(sdv[3]);
    *(ushort4*)(row + 4 * fl) = wm;
    *(ushort4*)(row + 128 + 4 * fl) = wn;
    *(ushort4*)(row + 256 + 4 * fl) = wx;
    *(ushort4*)(row + 384 + 4 * fl) = ws;
    if (fl == 0) {
      float degf = (float)dg;
      float sc = logf(fmaxf(degf, 1.0f) + 1.0f) / adl[0];
      scale[v] = sc;
      inv_scale[v] = 1.0f / sc;
    }
  }
}

// ------- fused: post GEMM (K=640, counted-vmcnt dbuf) + combine + lin GEMM + relu + next-Q GEMM -------
__global__ __launch_bounds__(512, 2) void k_fused(const unsigned short* __restrict__ X,
                                                   const unsigned char* __restrict__ Bimg,
                                                   const unsigned char* __restrict__ Limg,
                                                   const unsigned char* __restrict__ Qimg,
                                                   const float* __restrict__ scale,
                                                   const float* __restrict__ invs,
                                                   const float* __restrict__ biasg,
                                                   const float* __restrict__ lin_b,
                                                   unsigned short* __restrict__ Xh,
                                                   unsigned short* __restrict__ Qb,
                                                   float* __restrict__ Fout,
                                                   int M, int write_f32, int doC) {
  // phase A: buf b: A[16KB] @ b*65536, B[48KB] @ b*65536+16384
  // phase B: lin @0 (32KB), y @32768 (32KB)
  // phase C: h @65536 (32KB), Wq @98304 (32KB)
  __shared__ __align__(16) unsigned char lds[131072];
  int tid = threadIdx.x;
  int w = tid >> 6, lane = tid & 63;
  int wr = w >> 2, wc = w & 3;
  int l16 = lane & 15, lhi = lane >> 4;
  int row0 = blockIdx.x * 128;
  const char* Xb = (const char*)X;
  const char* srcA[2];
  unsigned dstA[2];
#pragma unroll
  for (int j = 0; j < 2; j++) {
    int off = (w * 2 + j) * 1024 + lane * 16;
    int r = off >> 7, pos = off & 127;
    int ch = (pos ^ ((r & 7) << 4)) >> 4;
    srcA[j] = Xb + (size_t)(row0 + r) * 1280 + ch * 16;
    dstA[j] = (w * 2 + j) * 1024;
  }
  const unsigned char* srcB = Bimg + w * 6144 + lane * 16;
  unsigned dstB = 16384 + w * 6144;

  f32x4 acc[4][6];
#pragma unroll
  for (int m = 0; m < 4; m++)
#pragma unroll
    for (int f = 0; f < 6; f++) acc[m][f] = (f32x4){0.f, 0.f, 0.f, 0.f};

#define STAGE_AB(buf, kt)                                                        \
  do {                                                                           \
    unsigned base = (buf) * 65536u;                                              \
    _Pragma("unroll") for (int j = 0; j < 2; j++)                                \
        gload16(srcA[j] + (kt) * 128, lds + base + dstA[j]);                     \
    _Pragma("unroll") for (int j = 0; j < 6; j++)                                \
        gload16(srcB + (size_t)(kt) * 49152 + j * 1024, lds + base + dstB + j * 1024); \
  } while (0)

#define COMPUTE_A(buf)                                                           \
  do {                                                                           \
    const unsigned char* LA = lds + (buf) * 65536u;                              \
    const unsigned char* LB = LA + 16384;                                        \
    _Pragma("unroll") for (int ks = 0; ks < 2; ks++) {                           \
      int pb = ks * 64 + lhi * 16;                                               \
      bf16x8 af[4], bfr[6];                                                      \
      _Pragma("unroll") for (int m = 0; m < 4; m++)                              \
          af[m] = rf128(LA, wr * 64 + m * 16 + l16, pb);                         \
      _Pragma("unroll") for (int f = 0; f < 6; f++)                              \
          bfr[f] = rf128(LB, (f >> 1) * 128 + wc * 32 + (f & 1) * 16 + l16, pb); \
      _Pragma("unroll") for (int m = 0; m < 4; m++)                              \
          _Pragma("unroll") for (int f = 0; f < 6; f++)                          \
              acc[m][f] =                                                        \
                  __builtin_amdgcn_mfma_f32_16x16x32_bf16(af[m], bfr[f], acc[m][f], 0, 0, 0); \
    }                                                                            \
  } while (0)

  // 2-deep pipeline with counted vmcnt: tile kt+1's 8 loads stay in flight across compute kt
  STAGE_AB(0, 0);
  STAGE_AB(1, 1);
  for (int kt = 0; kt < 10; kt++) {
    if (kt < 9) {
      asm volatile("s_waitcnt vmcnt(8)" ::: "memory");  // tile kt landed; kt+1 still in flight
    } else {
      asm volatile("s_waitcnt vmcnt(0)" ::: "memory");
    }
    __builtin_amdgcn_s_barrier();
    __builtin_amdgcn_sched_barrier(0);
    COMPUTE_A(kt & 1);
    __builtin_amdgcn_sched_barrier(0);
    __builtin_amdgcn_s_barrier();  // all waves done reading buf[kt&1]
    if (kt < 8) STAGE_AB(kt & 1, kt + 2);
  }

  // stage lin image into @0 (free); combine epilogue hides the load
#pragma unroll
  for (int j = 0; j < 4; j++) {
    int off = w * 4096 + j * 1024;
    gload16(Limg + off + lane * 16, lds + off);
  }
  // combine epilogue -> y into LDS @32768 (256B swizzled rows)
#pragma unroll
  for (int m = 0; m < 4; m++)
#pragma unroll
    for (int i = 0; i < 4; i++) {
      int rl = wr * 64 + m * 16 + lhi * 4 + i;
      int r = row0 + rl;
      float s = scale[r], iv = invs[r];
      int swz = (rl & 7) << 4;
#pragma unroll
      for (int j = 0; j < 2; j++) {
        int c = wc * 32 + j * 16 + l16;
        float v = acc[m][j][i] + s * acc[m][2 + j][i] + iv * acc[m][4 + j][i] + biasg[c] +
                  s * biasg[128 + c] + iv * biasg[256 + c];
        *(unsigned short*)(lds + 32768 + rl * 256 + ((2 * c) ^ swz)) = f2bf(v);
      }
    }
  __syncthreads();  // drains lin stage + makes y visible

  // issue next-layer Wq prefetch into @98304 (hides under phase B)
  if (doC) {
#pragma unroll
    for (int j = 0; j < 4; j++) {
      int off = w * 4096 + j * 1024;
      gload16(Qimg + off + lane * 16, lds + 98304 + off);
    }
  }

  // phase B: h = relu(y @ lin^T + lin_b)
  f32x4 acc2[4][2];
#pragma unroll
  for (int m = 0; m < 4; m++)
#pragma unroll
    for (int j = 0; j < 2; j++) acc2[m][j] = (f32x4){0.f, 0.f, 0.f, 0.f};
#pragma unroll
  for (int ks = 0; ks < 4; ks++) {
    int pb = ks * 64 + lhi * 16;
    bf16x8 af[4], bfr[2];
#pragma unroll
    for (int m = 0; m < 4; m++) af[m] = rf256(lds + 32768, wr * 64 + m * 16 + l16, pb);
#pragma unroll
    for (int j = 0; j < 2; j++) bfr[j] = rf256(lds, wc * 32 + j * 16 + l16, pb);
#pragma unroll
    for (int m = 0; m < 4; m++)
#pragma unroll
      for (int j = 0; j < 2; j++)
        acc2[m][j] = __builtin_amdgcn_mfma_f32_16x16x32_bf16(af[m], bfr[j], acc2[m][j], 0, 0, 0);
  }
  // h epilogue: write Xh global (+Fout), and h into LDS @65536 for phase C
#pragma unroll
  for (int m = 0; m < 4; m++)
#pragma unroll
    for (int j = 0; j < 2; j++)
#pragma unroll
      for (int i = 0; i < 4; i++) {
        int rl = wr * 64 + m * 16 + lhi * 4 + i;
        int r = row0 + rl;
        int c = wc * 32 + j * 16 + l16;
        float v = fmaxf(acc2[m][j][i] + lin_b[c], 0.0f);
        unsigned short hb = f2bf(v);
        Xh[(size_t)r * 640 + c] = hb;
        if (doC) *(unsigned short*)(lds + 65536 + rl * 256 + ((2 * c) ^ ((rl & 7) << 4))) = hb;
        if (write_f32 && r < M) Fout[(size_t)r * 128 + c] = v;
      }
  if (!doC) return;
  __syncthreads();  // h visible + Wq staged (vmcnt drained)

  // phase C: Qb_next = h @ Wq^T
  f32x4 acc3[4][2];
#pragma unroll
  for (int m = 0; m < 4; m++)
#pragma unroll
    for (int j = 0; j < 2; j++) acc3[m][j] = (f32x4){0.f, 0.f, 0.f, 0.f};
#pragma unroll
  for (int ks = 0; ks < 4; ks++) {
    int pb = ks * 64 + lhi * 16;
    bf16x8 af[4], bfr[2];
#pragma unroll
    for (int m = 0; m < 4; m++) af[m] = rf256(lds + 65536, wr * 64 + m * 16 + l16, pb);
#pragma unroll
    for (int j = 0; j < 2; j++) bfr[j] = rf256(lds + 98304, wc * 32 + j * 16 + l16, pb);
#pragma unroll
    for (int m = 0; m < 4; m++)
#pragma unroll
      for (int j = 0; j < 2; j++)
        acc3[m][j] = __builtin_amdgcn_mfma_f32_16x16x32_bf16(af[m], bfr[j], acc3[m][j], 0, 0, 0);
  }
#pragma unroll
  for (int m = 0; m < 4; m++)
#pragma unroll
    for (int j = 0; j < 2; j++)
#pragma unroll
      for (int i = 0; i < 4; i++) {
        int r = row0 + wr * 64 + m * 16 + lhi * 4 + i;
        int c = wc * 32 + j * 16 + l16;
        Qb[(size_t)r * 128 + c] = f2bf(acc3[m][j][i]);
      }
#undef STAGE_AB
#undef COMPUTE_A
}

// ---------------- host ----------------
extern "C" void kernel_launch(void* const* d_in, const int* in_sizes, int n_in,
                              void* d_out, int out_size, void* d_ws, size_t ws_size,
                              hipStream_t stream) {
  const float* x = (const float*)d_in[0];
  const int* eidx = (const int*)d_in[1];
  int n = in_sizes[0] / 128;
  int E = in_sizes[1] / 2;
  int n_pad = (n + 127) & ~127;
  const int* src = eidx;
  const int* dst = eidx + E;

  const float *pre_w[5], *pre_b[5], *adl[5], *post_w[5], *post_b[5], *lin_w[5], *lin_b[5];
  for (int i = 0; i < 5; i++) {
    pre_w[i] = (const float*)d_in[2 + i * 7 + 0];
    pre_b[i] = (const float*)d_in[2 + i * 7 + 1];
    adl[i] = (const float*)d_in[2 + i * 7 + 2];
    post_w[i] = (const float*)d_in[2 + i * 7 + 3];
    post_b[i] = (const float*)d_in[2 + i * 7 + 4];
    lin_w[i] = (const float*)d_in[2 + i * 7 + 5];
    lin_b[i] = (const float*)d_in[2 + i * 7 + 6];
  }

  char* ws = (char*)d_ws;
  size_t off = 0;
  auto alloc = [&](size_t bytes) {
    char* p = ws + off;
    off += (bytes + 255) & ~(size_t)255;
    return p;
  };
  unsigned short* X = (unsigned short*)alloc((size_t)n_pad * 640 * 2);  // [h | agg]
  unsigned short* Qb = (unsigned short*)alloc((size_t)n_pad * 128 * 2);
  float* scale = (float*)alloc((size_t)n_pad * 4);
  float* invs = (float*)alloc((size_t)n_pad * 4);
  int* deg = (int*)alloc((size_t)n * 4);
  int* row_start = (int*)alloc((size_t)(n + 1) * 4);
  int* cursor = (int*)alloc((size_t)n * 4);
  int* edge_src = (int*)alloc((size_t)E * 4);
  int nb = (n + 1023) / 1024;
  int* bsum = (int*)alloc((size_t)nb * 4);
  int* boff = (int*)alloc((size_t)nb * 4);
  float* Whg = (float*)alloc(3 * 128 * 128 * 4);
  unsigned char *Bpost[5], *Lin[5], *Qimg[5];
  float* biasg[5];
  for (int i = 0; i < 5; i++) {
    Bpost[i] = (unsigned char*)alloc(491520);
    Lin[i] = (unsigned char*)alloc(32768);
    Qimg[i] = (unsigned char*)alloc(32768);
    biasg[i] = (float*)alloc(384 * 4);
  }

  hipMemsetAsync(deg, 0, (size_t)n * 4, stream);
  k_hist<<<(E + 255) / 256, 256, 0, stream>>>(dst, deg, E);
  k_scan_part<<<nb, 256, 0, stream>>>(deg, bsum, n);
  k_scan_bsum<<<1, 64, 0, stream>>>(bsum, boff, row_start, nb, n);
  k_scan_final<<<nb, 256, 0, stream>>>(deg, boff, row_start, cursor, n);
  k_scatter<<<(E + 255) / 256, 256, 0, stream>>>(src, dst, cursor, edge_src, E);
  k_cast<<<(n * 32 + 255) / 256, 256, 0, stream>>>(x, X, n);
  for (int i = 0; i < 5; i++) {
    k_fold<<<192, 256, 0, stream>>>(post_w[i], pre_w[i], pre_b[i], post_b[i], Whg, biasg[i]);
    k_repack_post<<<(384 * 640 + 255) / 256, 256, 0, stream>>>(post_w[i], Whg, Bpost[i]);
    k_repack_lin<<<(128 * 128 + 255) / 256, 256, 0, stream>>>(lin_w[i], Lin[i]);
    k_repack_q<<<(128 * 128 + 255) / 256, 256, 0, stream>>>(pre_w[i], Qimg[i]);
  }

  int gblocks = n_pad / 128;
  k_gemm1<<<gblocks, 512, 0, stream>>>(X, Qimg[0], Qb);
  for (int L = 0; L < 5; L++) {
    k_agg<<<(n + 3) / 4, 256, 0, stream>>>(Qb, row_start, edge_src, X, pre_w[L], pre_b[L],
                                           adl[L], X, scale, invs, n);
    k_fused<<<gblocks, 512, 0, stream>>>(X, Bpost[L], Lin[L], (L < 4) ? Qimg[L + 1] : Qimg[0],
                                         scale, invs, biasg[L], lin_b[L], X, Qb, (float*)d_out,
                                         n, (L == 4) ? 1 : 0, (L < 4) ? 1 : 0);
  }
}